// Round 8
// baseline (520.419 us; speedup 1.0000x reference)
//
#include <hip/hip_runtime.h>
#include <hip/hip_bf16.h>
#include <math.h>
#include <stdint.h>

#define B_BATCH   1024
#define D_DIM     512
#define C_CLASSES 100000
#define BM        128
#define BN        128
#define BK        64                              // fp8: 64 B per row-tile
#define KITERS    (D_DIM / BK)                    // 8
#define MTILES    (B_BATCH / BM)                  // 8
#define NTILES    ((C_CLASSES + BN - 1) / BN)     // 782
#define NGROUPS   98                              // ceil(782/8)
#define GRID_G    (8 * 8 * NGROUPS)               // 6272 blocks (16 early-exit)
#define LOG2E     1.44269504088896340736f
#define COSM      0.87758256189037276f            // cos(0.5)
#define SINM      0.47942553860420301f            // sin(0.5)
#define NEG_LOG_EPS 69.07755278982137f            // -ln(1e-30)

typedef float f32x4 __attribute__((ext_vector_type(4)));
typedef long long i64t;

// pack float4 -> 4 x fp8 e4m3 (OCP on gfx950), HW RNE incl. subnormals
static __device__ __forceinline__ unsigned int pk4(float a, float b, float c, float d) {
    int p = __builtin_amdgcn_cvt_pk_fp8_f32(a, b, 0, false);   // low word
    p = __builtin_amdgcn_cvt_pk_fp8_f32(c, d, p, true);        // high word
    return (unsigned int)p;
}

// async 16B/lane global -> LDS (LDS dest = wave-uniform base + lane*16)
static __device__ __forceinline__ void gld16(const unsigned char* g, unsigned char* l) {
    __builtin_amdgcn_global_load_lds(
        (const __attribute__((address_space(1))) unsigned int*)g,
        (__attribute__((address_space(3))) unsigned int*)l, 16, 0, 0);
}

// ---------------- kernel 1: normalize embeddings -> fp8 A [1024 x 512] ----
__global__ __launch_bounds__(256) void norm_embed(const float* __restrict__ E,
                                                  unsigned char* __restrict__ Af8) {
    const int b = blockIdx.x;
    const int t = threadIdx.x;
    float2 v = ((const float2*)(E + (size_t)b * D_DIM))[t];
    float ss = v.x * v.x + v.y * v.y;
    #pragma unroll
    for (int off = 1; off < 64; off <<= 1) ss += __shfl_xor(ss, off);
    __shared__ float ws4[4];
    if ((t & 63) == 0) ws4[t >> 6] = ss;
    __syncthreads();
    float inv = rsqrtf(ws4[0] + ws4[1] + ws4[2] + ws4[3]);
    int p = __builtin_amdgcn_cvt_pk_fp8_f32(v.x * inv, v.y * inv, 0, false);
    ((unsigned short*)Af8)[(size_t)b * (D_DIM / 2) + t] = (unsigned short)(p & 0xffff);
}

// ---------------- kernel 1b: normalize weights -> fp8 [C x 512] -----------
// 2 rows per wave (4 independent float4 loads in flight); writes 51.2 MB.
__global__ __launch_bounds__(256) void norm_weight(const float* __restrict__ W,
                                                   unsigned char* __restrict__ Wf8) {
    const int wave = threadIdx.x >> 6;
    const int lane = threadIdx.x & 63;
    const int row0 = blockIdx.x * 8 + wave * 2;
    const int row1 = row0 + 1;
    const float4* s0 = (const float4*)(W + (size_t)row0 * D_DIM);
    const float4* s1 = (const float4*)(W + (size_t)row1 * D_DIM);
    float4 a0 = s0[lane];
    float4 a1 = s0[lane + 64];
    float4 b0 = s1[lane];
    float4 b1 = s1[lane + 64];
    float sa = a0.x*a0.x + a0.y*a0.y + a0.z*a0.z + a0.w*a0.w
             + a1.x*a1.x + a1.y*a1.y + a1.z*a1.z + a1.w*a1.w;
    float sb = b0.x*b0.x + b0.y*b0.y + b0.z*b0.z + b0.w*b0.w
             + b1.x*b1.x + b1.y*b1.y + b1.z*b1.z + b1.w*b1.w;
    #pragma unroll
    for (int off = 1; off < 64; off <<= 1) {
        sa += __shfl_xor(sa, off);
        sb += __shfl_xor(sb, off);
    }
    float ia = rsqrtf(sa), ib = rsqrtf(sb);
    unsigned int* d0 = (unsigned int*)(Wf8 + (size_t)row0 * D_DIM);
    unsigned int* d1 = (unsigned int*)(Wf8 + (size_t)row1 * D_DIM);
    d0[lane]      = pk4(a0.x*ia, a0.y*ia, a0.z*ia, a0.w*ia);
    d0[lane + 64] = pk4(a1.x*ia, a1.y*ia, a1.z*ia, a1.w*ia);
    d1[lane]      = pk4(b0.x*ib, b0.y*ib, b0.z*ib, b0.w*ib);
    d1[lane + 64] = pk4(b1.x*ib, b1.y*ib, b1.z*ib, b1.w*ib);
}

// epilogue per-element: clip, ArcFace margin (identity form, no libm),
// returns exp(s - 64)
static __device__ __forceinline__ float epi_term(float accv, int col, int lab,
                                                 float* __restrict__ st, int srow) {
    float c = fminf(1.f, fmaxf(-1.f, accv));
    if (col >= C_CLASSES) return 0.f;
    float s = c * 64.0f;
    if (col == lab) {
        float sn = sqrtf(fmaxf(0.f, 1.f - c * c));
        float nm = c * COSM - sn * SINM;          // cos(theta + m)
        if (c < -COSM) nm = -1.f;                 // theta + m > pi
        s = nm * 64.0f;
        st[srow] = s;                             // unique writer across grid
    }
    return exp2f((s - 64.0f) * LOG2E);
}

// ---------------- kernel 2: fp8 GEMM + margin + partial softmax -----------
// fp8 e4m3 at BK=64: SAME 17 KB LDS footprint as the 196 us bf16 round-6
// kernel (occupancy preserved) but HALF the barriers (8 iters), half the
// gld16 count, half the LDS bytes (b64 frags), half the frag VGPRs.
// 16-B-unit XOR swizzle (unit ^ (row&3)) spreads b64 frag reads; staging
// keeps gld16 contiguity (swizzle only remaps each lane's global column).
// XCD-colocating 1D grid (round 5): W fetched ~once into each XCD's L2.
__global__ __launch_bounds__(256) void gemm_cos(const unsigned char* __restrict__ Af8,
                                                const unsigned char* __restrict__ Wf8,
                                                const int* __restrict__ labels,
                                                float* __restrict__ st,
                                                float* __restrict__ partial) {
    __shared__ unsigned char As[BM * BK];   // 8 KiB
    __shared__ unsigned char Bs[BN * BK];   // 8 KiB
    __shared__ float rowSum[BM];
    __shared__ int   labs[BM];

    const int id = blockIdx.x;
    const int x  = id & 7;          // XCD slot
    const int s  = id >> 3;         // sequence on this XCD
    const int mt = s & 7;           // m-tile
    const int y  = x + 8 * (s >> 3);// n-tile: 8 consecutive s share y per XCD
    if (y >= NTILES) return;
    const int m0 = mt * BM;
    const int n0 = y * BN;

    const int tid = threadIdx.x;
    if (tid < BM) { labs[tid] = labels[m0 + tid]; rowSum[tid] = 0.f; }

    const int lane = tid & 63;
    const int wave = tid >> 6;
    const int wm = wave & 1, wn = wave >> 1;
    const int l15 = lane & 15, quad = lane >> 4;

    // staging: chunk c = 16 tile rows (16 x 64 B = 1024 B = one wave gld16).
    // lane i -> row i>>2, 16-B unit (i&3); swizzle: global unit = (i&3)^(row&3).
    const int rsub = lane >> 2;                          // 0..15
    const int swcol = (((lane & 3) ^ (rsub & 3)) * 16);  // swizzled source col
    const int c0 = wave * 2, c1 = c0 + 1;
    const unsigned char* gA0 = Af8 + (size_t)(m0 + c0 * 16 + rsub) * D_DIM + swcol;
    const unsigned char* gA1 = Af8 + (size_t)(m0 + c1 * 16 + rsub) * D_DIM + swcol;
    const int bR0 = min(n0 + c0 * 16 + rsub, C_CLASSES - 1);
    const int bR1 = min(n0 + c1 * 16 + rsub, C_CLASSES - 1);
    const unsigned char* gB0 = Wf8 + (size_t)bR0 * D_DIM + swcol;
    const unsigned char* gB1 = Wf8 + (size_t)bR1 * D_DIM + swcol;
    unsigned char* lA0 = &As[c0 * 1024];
    unsigned char* lA1 = &As[c1 * 1024];
    unsigned char* lB0 = &Bs[c0 * 1024];
    unsigned char* lB1 = &Bs[c1 * 1024];

    const f32x4 z = (f32x4){0.f, 0.f, 0.f, 0.f};
    f32x4 a00 = z, a01 = z, a02 = z, a03 = z;
    f32x4 a10 = z, a11 = z, a12 = z, a13 = z;
    f32x4 a20 = z, a21 = z, a22 = z, a23 = z;
    f32x4 a30 = z, a31 = z, a32 = z, a33 = z;

    // frag byte offsets: row r, kstep s, quad q -> r*64 + ((s*4+q)^((r&3)<<1))*8
    const int sw  = (l15 & 3) << 1;
    const int arow = (wm * 64 + l15) * BK;
    const int brow = (wn * 64 + l15) * BK;
    const int off0 = ((quad)     ^ sw) * 8;   // kstep 0
    const int off1 = ((4 + quad) ^ sw) * 8;   // kstep 1

    for (int kk = 0; kk < KITERS; ++kk) {
        __syncthreads();                     // prior frag reads done
        gld16(gA0, lA0); gld16(gA1, lA1);
        gld16(gB0, lB0); gld16(gB1, lB1);
        gA0 += BK; gA1 += BK; gB0 += BK; gB1 += BK;
        __syncthreads();                     // loads visible

        // ---- kstep 0 (k = kk*64 .. +31) ----
        i64t af0 = *(const i64t*)&As[arow + off0];
        i64t af1 = *(const i64t*)&As[arow + 16 * BK + off0];
        i64t af2 = *(const i64t*)&As[arow + 32 * BK + off0];
        i64t af3 = *(const i64t*)&As[arow + 48 * BK + off0];
        i64t bf0 = *(const i64t*)&Bs[brow + off0];
        i64t bf1 = *(const i64t*)&Bs[brow + 16 * BK + off0];
        i64t bf2 = *(const i64t*)&Bs[brow + 32 * BK + off0];
        i64t bf3 = *(const i64t*)&Bs[brow + 48 * BK + off0];

        a00 = __builtin_amdgcn_mfma_f32_16x16x32_fp8_fp8(af0, bf0, a00, 0, 0, 0);
        a01 = __builtin_amdgcn_mfma_f32_16x16x32_fp8_fp8(af0, bf1, a01, 0, 0, 0);
        a02 = __builtin_amdgcn_mfma_f32_16x16x32_fp8_fp8(af0, bf2, a02, 0, 0, 0);
        a03 = __builtin_amdgcn_mfma_f32_16x16x32_fp8_fp8(af0, bf3, a03, 0, 0, 0);
        a10 = __builtin_amdgcn_mfma_f32_16x16x32_fp8_fp8(af1, bf0, a10, 0, 0, 0);
        a11 = __builtin_amdgcn_mfma_f32_16x16x32_fp8_fp8(af1, bf1, a11, 0, 0, 0);
        a12 = __builtin_amdgcn_mfma_f32_16x16x32_fp8_fp8(af1, bf2, a12, 0, 0, 0);
        a13 = __builtin_amdgcn_mfma_f32_16x16x32_fp8_fp8(af1, bf3, a13, 0, 0, 0);
        a20 = __builtin_amdgcn_mfma_f32_16x16x32_fp8_fp8(af2, bf0, a20, 0, 0, 0);
        a21 = __builtin_amdgcn_mfma_f32_16x16x32_fp8_fp8(af2, bf1, a21, 0, 0, 0);
        a22 = __builtin_amdgcn_mfma_f32_16x16x32_fp8_fp8(af2, bf2, a22, 0, 0, 0);
        a23 = __builtin_amdgcn_mfma_f32_16x16x32_fp8_fp8(af2, bf3, a23, 0, 0, 0);
        a30 = __builtin_amdgcn_mfma_f32_16x16x32_fp8_fp8(af3, bf0, a30, 0, 0, 0);
        a31 = __builtin_amdgcn_mfma_f32_16x16x32_fp8_fp8(af3, bf1, a31, 0, 0, 0);
        a32 = __builtin_amdgcn_mfma_f32_16x16x32_fp8_fp8(af3, bf2, a32, 0, 0, 0);
        a33 = __builtin_amdgcn_mfma_f32_16x16x32_fp8_fp8(af3, bf3, a33, 0, 0, 0);

        // ---- kstep 1 (k = kk*64+32 .. +63) ----
        af0 = *(const i64t*)&As[arow + off1];
        af1 = *(const i64t*)&As[arow + 16 * BK + off1];
        af2 = *(const i64t*)&As[arow + 32 * BK + off1];
        af3 = *(const i64t*)&As[arow + 48 * BK + off1];
        bf0 = *(const i64t*)&Bs[brow + off1];
        bf1 = *(const i64t*)&Bs[brow + 16 * BK + off1];
        bf2 = *(const i64t*)&Bs[brow + 32 * BK + off1];
        bf3 = *(const i64t*)&Bs[brow + 48 * BK + off1];

        a00 = __builtin_amdgcn_mfma_f32_16x16x32_fp8_fp8(af0, bf0, a00, 0, 0, 0);
        a01 = __builtin_amdgcn_mfma_f32_16x16x32_fp8_fp8(af0, bf1, a01, 0, 0, 0);
        a02 = __builtin_amdgcn_mfma_f32_16x16x32_fp8_fp8(af0, bf2, a02, 0, 0, 0);
        a03 = __builtin_amdgcn_mfma_f32_16x16x32_fp8_fp8(af0, bf3, a03, 0, 0, 0);
        a10 = __builtin_amdgcn_mfma_f32_16x16x32_fp8_fp8(af1, bf0, a10, 0, 0, 0);
        a11 = __builtin_amdgcn_mfma_f32_16x16x32_fp8_fp8(af1, bf1, a11, 0, 0, 0);
        a12 = __builtin_amdgcn_mfma_f32_16x16x32_fp8_fp8(af1, bf2, a12, 0, 0, 0);
        a13 = __builtin_amdgcn_mfma_f32_16x16x32_fp8_fp8(af1, bf3, a13, 0, 0, 0);
        a20 = __builtin_amdgcn_mfma_f32_16x16x32_fp8_fp8(af2, bf0, a20, 0, 0, 0);
        a21 = __builtin_amdgcn_mfma_f32_16x16x32_fp8_fp8(af2, bf1, a21, 0, 0, 0);
        a22 = __builtin_amdgcn_mfma_f32_16x16x32_fp8_fp8(af2, bf2, a22, 0, 0, 0);
        a23 = __builtin_amdgcn_mfma_f32_16x16x32_fp8_fp8(af2, bf3, a23, 0, 0, 0);
        a30 = __builtin_amdgcn_mfma_f32_16x16x32_fp8_fp8(af3, bf0, a30, 0, 0, 0);
        a31 = __builtin_amdgcn_mfma_f32_16x16x32_fp8_fp8(af3, bf1, a31, 0, 0, 0);
        a32 = __builtin_amdgcn_mfma_f32_16x16x32_fp8_fp8(af3, bf2, a32, 0, 0, 0);
        a33 = __builtin_amdgcn_mfma_f32_16x16x32_fp8_fp8(af3, bf3, a33, 0, 0, 0);
    }

    const int colbase = n0 + wn * 64 + l15;

    #define EPIROW(A0, A1, A2, A3, MI)                                         \
    {                                                                          \
        _Pragma("unroll")                                                      \
        for (int r = 0; r < 4; ++r) {                                          \
            const int rloc = wm * 64 + (MI) * 16 + quad * 4 + r;               \
            const int lab = labs[rloc];                                        \
            float part = 0.f;                                                  \
            part += epi_term((A0)[r], colbase,      lab, st, m0 + rloc);       \
            part += epi_term((A1)[r], colbase + 16, lab, st, m0 + rloc);       \
            part += epi_term((A2)[r], colbase + 32, lab, st, m0 + rloc);       \
            part += epi_term((A3)[r], colbase + 48, lab, st, m0 + rloc);       \
            part += __shfl_xor(part, 1);                                       \
            part += __shfl_xor(part, 2);                                       \
            part += __shfl_xor(part, 4);                                       \
            part += __shfl_xor(part, 8);                                       \
            if (l15 == 0) atomicAdd(&rowSum[rloc], part);                      \
        }                                                                      \
    }

    EPIROW(a00, a01, a02, a03, 0)
    EPIROW(a10, a11, a12, a13, 1)
    EPIROW(a20, a21, a22, a23, 2)
    EPIROW(a30, a31, a32, a33, 3)
    #undef EPIROW

    __syncthreads();
    if (tid < BM) partial[(size_t)y * B_BATCH + m0 + tid] = rowSum[tid];
}

// ---------------- kernel 3: per-row combine + mean loss ----------------
__global__ __launch_bounds__(64) void reduce_loss(const float* __restrict__ partial,
                                                  const float* __restrict__ st,
                                                  float* __restrict__ out) {
    const int b = blockIdx.x;
    const int l = threadIdx.x;
    float L = 0.f;
    for (int t = l; t < NTILES; t += 64) L += partial[(size_t)t * B_BATCH + b];
    #pragma unroll
    for (int off = 1; off < 64; off <<= 1) L += __shfl_xor(L, off);
    if (l == 0) {
        float logp = st[b] - 64.0f - logf(L);
        float lossb = fminf(-logp, NEG_LOG_EPS) * (1.0f / (float)B_BATCH);
        atomicAdd(out, lossb);
    }
}

extern "C" void kernel_launch(void* const* d_in, const int* in_sizes, int n_in,
                              void* d_out, int out_size, void* d_ws, size_t ws_size,
                              hipStream_t stream) {
    const float* emb = (const float*)d_in[0];
    const float* wgt = (const float*)d_in[1];
    const int*   lab = (const int*)d_in[2];
    float* out = (float*)d_out;
    char* ws = (char*)d_ws;

    const size_t WF8_B = (size_t)C_CLASSES * D_DIM;      // 51,200,000
    const size_t AF8_B = (size_t)B_BATCH * D_DIM;        // 524,288

    unsigned char* Wf8 = (unsigned char*)ws;
    unsigned char* Af8 = (unsigned char*)(ws + WF8_B);
    float* st      = (float*)(ws + WF8_B + AF8_B);
    float* partial = (float*)(ws + WF8_B + AF8_B + 4096);

    hipMemsetAsync(d_out, 0, sizeof(float), stream);
    norm_embed<<<B_BATCH, 256, 0, stream>>>(emb, Af8);
    norm_weight<<<C_CLASSES / 8, 256, 0, stream>>>(wgt, Wf8);
    gemm_cos<<<GRID_G, 256, 0, stream>>>(Af8, Wf8, lab, st, partial);
    reduce_loss<<<B_BATCH, 64, 0, stream>>>(partial, st, out);
}

// Round 9
// 461.896 us; speedup vs baseline: 1.1267x; 1.1267x over previous
//
#include <hip/hip_runtime.h>
#include <hip/hip_bf16.h>
#include <math.h>
#include <stdint.h>

#define B_BATCH   1024
#define D_DIM     512
#define C_CLASSES 100000
#define BM        128
#define BN        128
#define BK        32
#define KITERS    (D_DIM / BK)                    // 16
#define MTILES    (B_BATCH / BM)                  // 8
#define NTILES    ((C_CLASSES + BN - 1) / BN)     // 782
#define NGROUPS   98                              // ceil(782/8)
#define GRID_G    (8 * 8 * NGROUPS)               // 6272 blocks (16 early-exit)
#define LOG2E     1.44269504088896340736f
#define COSM      0.87758256189037276f            // cos(0.5)
#define SINM      0.47942553860420301f            // sin(0.5)
#define NEG_LOG_EPS 69.07755278982137f            // -ln(1e-30)

typedef short bf16x8 __attribute__((ext_vector_type(8)));
typedef float f32x4  __attribute__((ext_vector_type(4)));

static __device__ __forceinline__ unsigned short f2bf(float f) {
    unsigned int u = __builtin_bit_cast(unsigned int, f);
    u += 0x7fffu + ((u >> 16) & 1u);              // round-to-nearest-even
    return (unsigned short)(u >> 16);
}

// pack 2 floats -> 2 bf16 by TRUNCATION with one v_perm_b32 (norm_weight is
// VALU-bound at ~50 ops/lane with manual RNE; trunc err ~2^-8 rel, loss err
// well under the 0.925 threshold)
static __device__ __forceinline__ unsigned int pk_bf16_trunc(float lo, float hi) {
    return __builtin_amdgcn_perm(__builtin_bit_cast(unsigned int, hi),
                                 __builtin_bit_cast(unsigned int, lo),
                                 0x07060302u);
}

// async 16B/lane global -> LDS (LDS dest = wave-uniform base + lane*16)
static __device__ __forceinline__ void gld16(const unsigned short* g, unsigned short* l) {
    __builtin_amdgcn_global_load_lds(
        (const __attribute__((address_space(1))) unsigned int*)g,
        (__attribute__((address_space(3))) unsigned int*)l, 16, 0, 0);
}

// ---------------- kernel 1: normalize embeddings -> bf16 A [1024 x 512] ---
__global__ __launch_bounds__(256) void norm_embed(const float* __restrict__ E,
                                                  unsigned short* __restrict__ Abf) {
    const int b = blockIdx.x;
    const int t = threadIdx.x;
    float2 v = ((const float2*)(E + (size_t)b * D_DIM))[t];
    float ss = v.x * v.x + v.y * v.y;
    #pragma unroll
    for (int off = 1; off < 64; off <<= 1) ss += __shfl_xor(ss, off);
    __shared__ float ws4[4];
    if ((t & 63) == 0) ws4[t >> 6] = ss;
    __syncthreads();
    float inv = rsqrtf(ws4[0] + ws4[1] + ws4[2] + ws4[3]);
    unsigned int packed = (unsigned int)f2bf(v.x * inv) |
                          ((unsigned int)f2bf(v.y * inv) << 16);
    ((unsigned int*)Abf)[(size_t)b * (D_DIM / 2) + t] = packed;
}

// ---------------- kernel 1b: normalize weights -> bf16 [C x 512] ----------
// 2 rows/wave, perm-based trunc pack: 4 VALU per 8 elems (was ~32).
__global__ __launch_bounds__(256) void norm_weight(const float* __restrict__ W,
                                                   unsigned short* __restrict__ Wbf) {
    const int wave = threadIdx.x >> 6;
    const int lane = threadIdx.x & 63;
    const int row0 = blockIdx.x * 8 + wave * 2;
    const int row1 = row0 + 1;
    const float4* s0 = (const float4*)(W + (size_t)row0 * D_DIM);
    const float4* s1 = (const float4*)(W + (size_t)row1 * D_DIM);
    float4 a0 = s0[lane];
    float4 a1 = s0[lane + 64];
    float4 b0 = s1[lane];
    float4 b1 = s1[lane + 64];
    float sa = a0.x*a0.x + a0.y*a0.y + a0.z*a0.z + a0.w*a0.w
             + a1.x*a1.x + a1.y*a1.y + a1.z*a1.z + a1.w*a1.w;
    float sb = b0.x*b0.x + b0.y*b0.y + b0.z*b0.z + b0.w*b0.w
             + b1.x*b1.x + b1.y*b1.y + b1.z*b1.z + b1.w*b1.w;
    #pragma unroll
    for (int off = 1; off < 64; off <<= 1) {
        sa += __shfl_xor(sa, off);
        sb += __shfl_xor(sb, off);
    }
    float ia = rsqrtf(sa), ib = rsqrtf(sb);
    uint2* d0 = (uint2*)(Wbf + (size_t)row0 * D_DIM);
    uint2* d1 = (uint2*)(Wbf + (size_t)row1 * D_DIM);
    uint2 oa0 = {pk_bf16_trunc(a0.x*ia, a0.y*ia), pk_bf16_trunc(a0.z*ia, a0.w*ia)};
    uint2 oa1 = {pk_bf16_trunc(a1.x*ia, a1.y*ia), pk_bf16_trunc(a1.z*ia, a1.w*ia)};
    uint2 ob0 = {pk_bf16_trunc(b0.x*ib, b0.y*ib), pk_bf16_trunc(b0.z*ib, b0.w*ib)};
    uint2 ob1 = {pk_bf16_trunc(b1.x*ib, b1.y*ib), pk_bf16_trunc(b1.z*ib, b1.w*ib)};
    d0[lane] = oa0; d0[lane + 64] = oa1;
    d1[lane] = ob0; d1[lane + 64] = ob1;
}

// epilogue per-element: clip, ArcFace margin (identity form, no libm),
// returns exp(s - 64)
static __device__ __forceinline__ float epi_term(float accv, int col, int lab,
                                                 float* __restrict__ st, int srow) {
    float c = fminf(1.f, fmaxf(-1.f, accv));
    if (col >= C_CLASSES) return 0.f;
    float s = c * 64.0f;
    if (col == lab) {
        float sn = sqrtf(fmaxf(0.f, 1.f - c * c));
        float nm = c * COSM - sn * SINM;          // cos(theta + m)
        if (c < -COSM) nm = -1.f;                 // theta + m > pi
        s = nm * 64.0f;
        st[srow] = s;                             // unique writer across grid
    }
    return exp2f((s - 64.0f) * LOG2E);
}

// ---------------- kernel 2: bf16 GEMM + margin + partial softmax ----------
// Round-6 structure verbatim (best measured: 196 us; r7 conflict-free and r8
// fp8 byte-halving both regressed -> the loop is latency-bound, matching the
// m97-plateau evidence). ONE experiment this round: __launch_bounds__(256,4)
// caps unified regs at 128/thread (64 AGPR acc + <=64 VGPR) -> 4 blocks/CU
// instead of 3 = one more independent barrier group to overlap the drains.
// Spill detector: WRITE_SIZE (must stay ~3.2 MB).
__global__ __launch_bounds__(256, 4) void gemm_cos(const unsigned short* __restrict__ Abf,
                                                   const unsigned short* __restrict__ Wbf,
                                                   const int* __restrict__ labels,
                                                   float* __restrict__ st,
                                                   float* __restrict__ partial) {
    __shared__ unsigned short As[BM * BK];   // 8 KiB, unpadded (global_load_lds layout)
    __shared__ unsigned short Bs[BN * BK];   // 8 KiB
    __shared__ float rowSum[BM];
    __shared__ int   labs[BM];

    const int id = blockIdx.x;
    const int x  = id & 7;          // XCD slot
    const int s  = id >> 3;         // sequence on this XCD
    const int mt = s & 7;           // m-tile
    const int y  = x + 8 * (s >> 3);// n-tile: 8 consecutive s share y per XCD
    if (y >= NTILES) return;
    const int m0 = mt * BM;
    const int n0 = y * BN;

    const int tid = threadIdx.x;
    if (tid < BM) { labs[tid] = labels[m0 + tid]; rowSum[tid] = 0.f; }

    const int lane = tid & 63;
    const int wave = tid >> 6;
    const int wm = wave & 1, wn = wave >> 1;
    const int l15 = lane & 15, quad = lane >> 4;

    // staging: wave w stages chunks (2w),(2w+1); chunk c = tile rows [16c,16c+16)
    const int rsub = lane >> 2;
    const int cg   = (lane & 3) * 8;
    const int c0 = wave * 2, c1 = wave * 2 + 1;
    const unsigned short* gA0 = Abf + (size_t)(m0 + c0 * 16 + rsub) * D_DIM + cg;
    const unsigned short* gA1 = Abf + (size_t)(m0 + c1 * 16 + rsub) * D_DIM + cg;
    const int bR0 = min(n0 + c0 * 16 + rsub, C_CLASSES - 1);
    const int bR1 = min(n0 + c1 * 16 + rsub, C_CLASSES - 1);
    const unsigned short* gB0 = Wbf + (size_t)bR0 * D_DIM + cg;
    const unsigned short* gB1 = Wbf + (size_t)bR1 * D_DIM + cg;
    unsigned short* lA0 = &As[c0 * 512];
    unsigned short* lA1 = &As[c1 * 512];
    unsigned short* lB0 = &Bs[c0 * 512];
    unsigned short* lB1 = &Bs[c1 * 512];

    const f32x4 z = (f32x4){0.f, 0.f, 0.f, 0.f};
    f32x4 a00 = z, a01 = z, a02 = z, a03 = z;
    f32x4 a10 = z, a11 = z, a12 = z, a13 = z;
    f32x4 a20 = z, a21 = z, a22 = z, a23 = z;
    f32x4 a30 = z, a31 = z, a32 = z, a33 = z;

    const int aro = (wm * 64 + l15) * BK + quad * 8;
    const int bro = (wn * 64 + l15) * BK + quad * 8;

    for (int kk = 0; kk < KITERS; ++kk) {
        __syncthreads();                     // prior frag reads done
        gld16(gA0, lA0); gld16(gA1, lA1);
        gld16(gB0, lB0); gld16(gB1, lB1);
        gA0 += BK; gA1 += BK; gB0 += BK; gB1 += BK;
        __syncthreads();                     // loads visible

        bf16x8 af0 = *(const bf16x8*)&As[aro];
        bf16x8 af1 = *(const bf16x8*)&As[aro + 16 * BK];
        bf16x8 af2 = *(const bf16x8*)&As[aro + 32 * BK];
        bf16x8 af3 = *(const bf16x8*)&As[aro + 48 * BK];
        bf16x8 bf0 = *(const bf16x8*)&Bs[bro];
        bf16x8 bf1 = *(const bf16x8*)&Bs[bro + 16 * BK];
        bf16x8 bf2 = *(const bf16x8*)&Bs[bro + 32 * BK];
        bf16x8 bf3 = *(const bf16x8*)&Bs[bro + 48 * BK];

        a00 = __builtin_amdgcn_mfma_f32_16x16x32_bf16(af0, bf0, a00, 0, 0, 0);
        a01 = __builtin_amdgcn_mfma_f32_16x16x32_bf16(af0, bf1, a01, 0, 0, 0);
        a02 = __builtin_amdgcn_mfma_f32_16x16x32_bf16(af0, bf2, a02, 0, 0, 0);
        a03 = __builtin_amdgcn_mfma_f32_16x16x32_bf16(af0, bf3, a03, 0, 0, 0);
        a10 = __builtin_amdgcn_mfma_f32_16x16x32_bf16(af1, bf0, a10, 0, 0, 0);
        a11 = __builtin_amdgcn_mfma_f32_16x16x32_bf16(af1, bf1, a11, 0, 0, 0);
        a12 = __builtin_amdgcn_mfma_f32_16x16x32_bf16(af1, bf2, a12, 0, 0, 0);
        a13 = __builtin_amdgcn_mfma_f32_16x16x32_bf16(af1, bf3, a13, 0, 0, 0);
        a20 = __builtin_amdgcn_mfma_f32_16x16x32_bf16(af2, bf0, a20, 0, 0, 0);
        a21 = __builtin_amdgcn_mfma_f32_16x16x32_bf16(af2, bf1, a21, 0, 0, 0);
        a22 = __builtin_amdgcn_mfma_f32_16x16x32_bf16(af2, bf2, a22, 0, 0, 0);
        a23 = __builtin_amdgcn_mfma_f32_16x16x32_bf16(af2, bf3, a23, 0, 0, 0);
        a30 = __builtin_amdgcn_mfma_f32_16x16x32_bf16(af3, bf0, a30, 0, 0, 0);
        a31 = __builtin_amdgcn_mfma_f32_16x16x32_bf16(af3, bf1, a31, 0, 0, 0);
        a32 = __builtin_amdgcn_mfma_f32_16x16x32_bf16(af3, bf2, a32, 0, 0, 0);
        a33 = __builtin_amdgcn_mfma_f32_16x16x32_bf16(af3, bf3, a33, 0, 0, 0);
    }

    const int colbase = n0 + wn * 64 + l15;

    #define EPIROW(A0, A1, A2, A3, MI)                                         \
    {                                                                          \
        _Pragma("unroll")                                                      \
        for (int r = 0; r < 4; ++r) {                                          \
            const int rloc = wm * 64 + (MI) * 16 + quad * 4 + r;               \
            const int lab = labs[rloc];                                        \
            float part = 0.f;                                                  \
            part += epi_term((A0)[r], colbase,      lab, st, m0 + rloc);       \
            part += epi_term((A1)[r], colbase + 16, lab, st, m0 + rloc);       \
            part += epi_term((A2)[r], colbase + 32, lab, st, m0 + rloc);       \
            part += epi_term((A3)[r], colbase + 48, lab, st, m0 + rloc);       \
            part += __shfl_xor(part, 1);                                       \
            part += __shfl_xor(part, 2);                                       \
            part += __shfl_xor(part, 4);                                       \
            part += __shfl_xor(part, 8);                                       \
            if (l15 == 0) atomicAdd(&rowSum[rloc], part);                      \
        }                                                                      \
    }

    EPIROW(a00, a01, a02, a03, 0)
    EPIROW(a10, a11, a12, a13, 1)
    EPIROW(a20, a21, a22, a23, 2)
    EPIROW(a30, a31, a32, a33, 3)
    #undef EPIROW

    __syncthreads();
    if (tid < BM) partial[(size_t)y * B_BATCH + m0 + tid] = rowSum[tid];
}

// ---------------- kernel 3: per-row combine + mean loss ----------------
__global__ __launch_bounds__(64) void reduce_loss(const float* __restrict__ partial,
                                                  const float* __restrict__ st,
                                                  float* __restrict__ out) {
    const int b = blockIdx.x;
    const int l = threadIdx.x;
    float L = 0.f;
    for (int t = l; t < NTILES; t += 64) L += partial[(size_t)t * B_BATCH + b];
    #pragma unroll
    for (int off = 1; off < 64; off <<= 1) L += __shfl_xor(L, off);
    if (l == 0) {
        float logp = st[b] - 64.0f - logf(L);
        float lossb = fminf(-logp, NEG_LOG_EPS) * (1.0f / (float)B_BATCH);
        atomicAdd(out, lossb);
    }
}

extern "C" void kernel_launch(void* const* d_in, const int* in_sizes, int n_in,
                              void* d_out, int out_size, void* d_ws, size_t ws_size,
                              hipStream_t stream) {
    const float* emb = (const float*)d_in[0];
    const float* wgt = (const float*)d_in[1];
    const int*   lab = (const int*)d_in[2];
    float* out = (float*)d_out;
    char* ws = (char*)d_ws;

    const size_t WBF_B = (size_t)C_CLASSES * D_DIM * 2;  // 102,400,000
    const size_t ABF_B = (size_t)B_BATCH * D_DIM * 2;    // 1,048,576

    unsigned short* Wbf = (unsigned short*)ws;
    unsigned short* Abf = (unsigned short*)(ws + WBF_B);
    float* st      = (float*)(ws + WBF_B + ABF_B);
    float* partial = (float*)(ws + WBF_B + ABF_B + 4096);

    hipMemsetAsync(d_out, 0, sizeof(float), stream);
    norm_embed<<<B_BATCH, 256, 0, stream>>>(emb, Abf);
    norm_weight<<<C_CLASSES / 8, 256, 0, stream>>>(wgt, Wbf);
    gemm_cos<<<GRID_G, 256, 0, stream>>>(Abf, Wbf, lab, st, partial);
    reduce_loss<<<B_BATCH, 64, 0, stream>>>(partial, st, out);
}